// Round 7
// baseline (834.342 us; speedup 1.0000x reference)
//
#include <hip/hip_runtime.h>
#include <math.h>

// hipcc defaults to -ffp-contract=fast; that would fuse our mul+add pairs
// into FMAs and break bit-exactness vs XLA. Kill contraction for everything
// defined below (scalar helpers additionally use __fmul_rn/__fadd_rn).
#pragma clang fp contract(off)

#define NSTEPS 3000
#define NWALK  1048576
#define BLOCK  256
#define NBD    (NWALK / (BLOCK * 2))  // 2048 blocks: one walker PAIR per lane
#define NDENSE 8                      // dense rounds cover t in [0, 512)
#define CHUNK  64
#define NBT    4096                   // tail grid: 16384 waves
#define NKEYS  3072

typedef float v2f __attribute__((ext_vector_type(2)));

// Ping-pong survivor lists (i, p-bits), per-round counts, precomputed keys.
__device__ uint2    g_list[2][NWALK];
__device__ uint32_t g_cnt[16];
__device__ uint2    g_keys[NKEYS];

// Threefry-2x32, 20 rounds, exactly JAX's schedule.
__device__ __forceinline__ void tf2x32(uint32_t k0, uint32_t k1,
                                       uint32_t x0, uint32_t x1,
                                       uint32_t& o0, uint32_t& o1) {
  uint32_t ks2 = k0 ^ k1 ^ 0x1BD11BDAu;
  x0 += k0; x1 += k1;
#define TFR(r) { x0 += x1; x1 = (x1 << r) | (x1 >> (32 - r)); x1 ^= x0; }
  TFR(13) TFR(15) TFR(26) TFR(6)
  x0 += k1;  x1 += ks2 + 1u;
  TFR(17) TFR(29) TFR(16) TFR(24)
  x0 += ks2; x1 += k0 + 2u;
  TFR(13) TFR(15) TFR(26) TFR(6)
  x0 += k0;  x1 += k1 + 3u;
  TFR(17) TFR(29) TFR(16) TFR(24)
  x0 += k1;  x1 += ks2 + 4u;
  TFR(13) TFR(15) TFR(26) TFR(6)
  x0 += ks2; x1 += k0 + 5u;
#undef TFR
  o0 = x0; o1 = x1;
}

__global__ void init_kernel() {   // <<<NKEYS/256, 256>>>
  int t = blockIdx.x * 256 + threadIdx.x;
  uint32_t a, b;
  tf2x32(0u, 0u, 0u, (uint32_t)t, a, b);
  g_keys[t] = make_uint2(a, b);
  if (blockIdx.x == 0 && threadIdx.x < 16) g_cnt[threadIdx.x] = 0u;
}

// ---------- scalar reference path (used by tail; bit-exact, proven R3-R6) ----
__device__ __forceinline__ float xla_cpu_log_f32(float s) {
  uint32_t bits = __float_as_uint(s);
  int emm0 = (int)(bits >> 23) - 0x7f;
  float e = __fadd_rn((float)emm0, 1.0f);
  float m = __uint_as_float((bits & 0x007fffffu) | 0x3f000000u);
  bool mlt = m < 0.70710677f;
  float tmp = mlt ? m : 0.0f;
  float x = __fsub_rn(m, 1.0f);
  e = __fsub_rn(e, mlt ? 1.0f : 0.0f);
  x = __fadd_rn(x, tmp);
  float x2 = __fmul_rn(x, x);
  float x3 = __fmul_rn(x2, x);
  float y, y1, y2;
  y  = __fadd_rn(__fmul_rn(7.0376836292e-2f,  x), -1.1514610310e-1f);
  y1 = __fadd_rn(__fmul_rn(-1.2420140846e-1f, x),  1.4249322787e-1f);
  y2 = __fadd_rn(__fmul_rn(2.0000714765e-1f,  x), -2.4999993993e-1f);
  y  = __fadd_rn(__fmul_rn(y,  x),  1.1676998740e-1f);
  y1 = __fadd_rn(__fmul_rn(y1, x), -1.6668057665e-1f);
  y2 = __fadd_rn(__fmul_rn(y2, x),  3.3333331174e-1f);
  y  = __fadd_rn(__fmul_rn(y, x3), y1);
  y  = __fadd_rn(__fmul_rn(y, x3), y2);
  y  = __fmul_rn(y, x3);
  y1 = __fmul_rn(e, -2.12194440e-4f);
  tmp = __fmul_rn(x2, 0.5f);
  y  = __fadd_rn(y, y1);
  x  = __fsub_rn(x, tmp);
  y2 = __fmul_rn(e, 0.693359375f);
  x  = __fadd_rn(x, y);
  x  = __fadd_rn(x, y2);
  return x;
}

__device__ __forceinline__ float xla_erfinv_f32(float x) {
  float s = __fmul_rn(__fsub_rn(1.0f, x), __fadd_rn(1.0f, x));
  float w = -xla_cpu_log_f32(s);
  float p;
  if (w < 5.0f) {
    float v = __fsub_rn(w, 2.5f);
    p = 2.81022636e-08f;
    p = __fadd_rn(__fmul_rn(p, v), 3.43273939e-07f);
    p = __fadd_rn(__fmul_rn(p, v), -3.5233877e-06f);
    p = __fadd_rn(__fmul_rn(p, v), -4.39150654e-06f);
    p = __fadd_rn(__fmul_rn(p, v), 0.00021858087f);
    p = __fadd_rn(__fmul_rn(p, v), -0.00125372503f);
    p = __fadd_rn(__fmul_rn(p, v), -0.00417768164f);
    p = __fadd_rn(__fmul_rn(p, v), 0.246640727f);
    p = __fadd_rn(__fmul_rn(p, v), 1.50140941f);
  } else {
    float v = __fsub_rn(__fsqrt_rn(w), 3.0f);
    p = -0.000200214257f;
    p = __fadd_rn(__fmul_rn(p, v), 0.000100950558f);
    p = __fadd_rn(__fmul_rn(p, v), 0.00134934322f);
    p = __fadd_rn(__fmul_rn(p, v), -0.00367342844f);
    p = __fadd_rn(__fmul_rn(p, v), 0.00573950773f);
    p = __fadd_rn(__fmul_rn(p, v), -0.0076224613f);
    p = __fadd_rn(__fmul_rn(p, v), 0.00943887047f);
    p = __fadd_rn(__fmul_rn(p, v), 1.00167406f);
    p = __fadd_rn(__fmul_rn(p, v), 2.83297682f);
  }
  return __fmul_rn(p, x);
}

__device__ __forceinline__ float normal_from_bits(uint32_t bits) {
  const float MINVAL = __uint_as_float(0xBF7FFFFFu);
  float f = __uint_as_float((bits >> 9) | 0x3F800000u) - 1.0f;
  float u = __fadd_rn(__fmul_rn(f, 2.0f), MINVAL);
  u = fmaxf(MINVAL, u);
  const float SQRT2 = __uint_as_float(0x3FB504F3u);
  return __fmul_rn(SQRT2, xla_erfinv_f32(u));
}

// ---------- packed (2-walker) path: v_pk_mul_f32/v_pk_add_f32 are two IEEE
// f32 ops -> bit-identical per component. Same op sequence as scalar path.
__device__ __forceinline__ v2f xla_cpu_log_v2(v2f s) {
  uint32_t bx = __float_as_uint(s.x), by = __float_as_uint(s.y);
  v2f e; e.x = (float)((int)(bx >> 23) - 0x7f); e.y = (float)((int)(by >> 23) - 0x7f);
  e = e + 1.0f;
  v2f m; m.x = __uint_as_float((bx & 0x007fffffu) | 0x3f000000u);
         m.y = __uint_as_float((by & 0x007fffffu) | 0x3f000000u);
  bool cx = m.x < 0.70710677f, cy = m.y < 0.70710677f;
  v2f tmp; tmp.x = cx ? m.x : 0.0f; tmp.y = cy ? m.y : 0.0f;
  v2f x = m - 1.0f;
  e.x = e.x - (cx ? 1.0f : 0.0f);
  e.y = e.y - (cy ? 1.0f : 0.0f);
  x = x + tmp;
  v2f x2 = x * x;
  v2f x3 = x2 * x;
  v2f y, y1, y2, t;
  t = 7.0376836292e-2f * x;  y  = t + -1.1514610310e-1f;
  t = -1.2420140846e-1f * x; y1 = t + 1.4249322787e-1f;
  t = 2.0000714765e-1f * x;  y2 = t + -2.4999993993e-1f;
  t = y * x;  y  = t + 1.1676998740e-1f;
  t = y1 * x; y1 = t + -1.6668057665e-1f;
  t = y2 * x; y2 = t + 3.3333331174e-1f;
  t = y * x3; y = t + y1;
  t = y * x3; y = t + y2;
  y = y * x3;
  y1 = e * -2.12194440e-4f;
  tmp = x2 * 0.5f;
  y = y + y1;
  x = x - tmp;
  y2 = e * 0.693359375f;
  x = x + y;
  x = x + y2;
  return x;
}

#define VSTEP(P, V, C) { v2f _t = (P) * (V); (P) = _t + (C); }

__device__ __forceinline__ v2f normal_v2(uint32_t bitsA, uint32_t bitsB) {
  const float MINVAL = __uint_as_float(0xBF7FFFFFu);
  v2f f; f.x = __uint_as_float((bitsA >> 9) | 0x3F800000u);
         f.y = __uint_as_float((bitsB >> 9) | 0x3F800000u);
  f = f - 1.0f;
  v2f u = f * 2.0f;
  u = u + MINVAL;
  u.x = fmaxf(MINVAL, u.x);
  u.y = fmaxf(MINVAL, u.y);
  v2f sa = 1.0f - u;
  v2f sb = 1.0f + u;
  v2f s = sa * sb;
  v2f w = -xla_cpu_log_v2(s);
  // branchless: both Horners, per-component select (identical to branchy)
  v2f va = w - 2.5f;
  v2f pa = (v2f)2.81022636e-08f;
  VSTEP(pa, va, 3.43273939e-07f)  VSTEP(pa, va, -3.5233877e-06f)
  VSTEP(pa, va, -4.39150654e-06f) VSTEP(pa, va, 0.00021858087f)
  VSTEP(pa, va, -0.00125372503f)  VSTEP(pa, va, -0.00417768164f)
  VSTEP(pa, va, 0.246640727f)     VSTEP(pa, va, 1.50140941f)
  v2f sq; sq.x = __fsqrt_rn(w.x); sq.y = __fsqrt_rn(w.y);
  v2f vb = sq - 3.0f;
  v2f pb = (v2f)-0.000200214257f;
  VSTEP(pb, vb, 0.000100950558f)  VSTEP(pb, vb, 0.00134934322f)
  VSTEP(pb, vb, -0.00367342844f)  VSTEP(pb, vb, 0.00573950773f)
  VSTEP(pb, vb, -0.0076224613f)   VSTEP(pb, vb, 0.00943887047f)
  VSTEP(pb, vb, 1.00167406f)      VSTEP(pb, vb, 2.83297682f)
  v2f r; r.x = (w.x < 5.0f) ? pa.x : pb.x;
         r.y = (w.y < 5.0f) ? pa.y : pb.y;
  v2f ev = r * u;                 // erfinv = p * x
  const float SQRT2 = __uint_as_float(0x3FB504F3u);
  v2f z = SQRT2 * ev;
  return z;
}

// Dense compaction round: one walker PAIR per lane, chunk [t0,t0+64).
// Branch-free inner loop (deferred output writes); survivors wave-appended.
__global__ __launch_bounds__(BLOCK)
void ddm_round(const float* __restrict__ sv_p, const float* __restrict__ rate_p,
               const float* __restrict__ ndt_p, const float* __restrict__ thr_p,
               const float* __restrict__ noise_p, const float* __restrict__ dt_p,
               const int* __restrict__ nw_p, float* __restrict__ out,
               int round, int t0) {
  __shared__ uint2 skeys[CHUNK];
  if (threadIdx.x < CHUNK) {
    uint32_t a, b;
    tf2x32(0u, 0u, 0u, (uint32_t)(t0 + threadIdx.x), a, b);
    skeys[threadIdx.x] = make_uint2(a, b);
  }
  __syncthreads();

  int nw = *nw_p;
  uint32_t count = (round == 0) ? (uint32_t)nw : g_cnt[round];
  uint32_t sA = (blockIdx.x * BLOCK + threadIdx.x) * 2u;
  uint32_t sB = sA + 1u;
  bool inA = sA < count, inB = sB < count;
  if (__ballot(inA) == 0ull) return;

  float sv = *sv_p, rate = *rate_p, ndt = *ndt_p, thr = *thr_p,
        noise = *noise_p, dt = *dt_p;
  float rate_dt = __fmul_rn(rate, dt);
  float sqrt_dt = __fsqrt_rn(dt);

  int iA = 0, iB = 0;
  v2f p; p.x = sv; p.y = sv;     // round0: zeros + starting_value == sv
  if (round == 0) { iA = (int)sA; iB = (int)sB; }
  else {
    if (inA) { uint2 e = g_list[round & 1][sA]; iA = (int)e.x; p.x = __uint_as_float(e.y); }
    if (inB) { uint2 e = g_list[round & 1][sB]; iB = (int)e.x; p.y = __uint_as_float(e.y); }
  }
  bool aliveA = inA, aliveB = inB;
  int rA = -1, rB = -1;

  for (int s = 0; s < CHUNK; ++s) {
    uint2 k = skeys[s];                   // wave-uniform: LDS broadcast
    uint32_t a1, a2, b1, b2;
    tf2x32(k.x, k.y, 0u, (uint32_t)iA, a1, a2);
    tf2x32(k.x, k.y, 0u, (uint32_t)iB, b1, b2);
    v2f z = normal_v2(a1 ^ a2, b1 ^ b2);
    v2f q0 = noise * z;
    v2f q1 = rate_dt + q0;
    v2f q = q1 * sqrt_dt;
    v2f pn = p + q;
    p.x = aliveA ? pn.x : p.x;            // freeze after crossing
    p.y = aliveB ? pn.y : p.y;
    bool cA = aliveA & !(fabsf(p.x) < thr);
    bool cB = aliveB & !(fabsf(p.y) < thr);
    rA = cA ? s : rA;  rB = cB ? s : rB;
    aliveA = aliveA & !cA;  aliveB = aliveB & !cB;
  }

  if (inA & !aliveA) {
    float rts = (float)(t0 + rA + 1);     // exact int == accumulated +1.0f
    out[iA] = __fadd_rn(ndt, __fmul_rn(rts, dt));
    out[nw + iA] = (p.x <= -thr) ? 0.0f : 1.0f;
  }
  if (inB & !aliveB) {
    float rts = (float)(t0 + rB + 1);
    out[iB] = __fadd_rn(ndt, __fmul_rn(rts, dt));
    out[nw + iB] = (p.y <= -thr) ? 0.0f : 1.0f;
  }

  int lane = threadIdx.x & 63;
  uint64_t mA = __ballot(aliveA);
  uint64_t mB = __ballot(aliveB);
  uint32_t nA = (uint32_t)__popcll(mA);
  uint32_t tot = nA + (uint32_t)__popcll(mB);
  if (tot) {                              // one atomic per wave; order-free
    int leader = __ffsll((unsigned long long)(mA | mB)) - 1;
    uint32_t base = 0;
    if (lane == leader) base = atomicAdd(&g_cnt[round + 1], tot);
    base = (uint32_t)__shfl((int)base, leader);
    uint64_t below = (1ull << lane) - 1ull;
    if (aliveA)
      g_list[(round + 1) & 1][base + (uint32_t)__popcll(mA & below)] =
          make_uint2((uint32_t)iA, __float_as_uint(p.x));
    if (aliveB)
      g_list[(round + 1) & 1][base + nA + (uint32_t)__popcll(mB & below)] =
          make_uint2((uint32_t)iB, __float_as_uint(p.y));
  }
}

// Tail: one walker per wave; 64 q's computed in parallel per macro-step,
// branchless wave-uniform exact sequential scan (freeze + first-cross index).
__global__ __launch_bounds__(BLOCK)
void ddm_tail(const float* __restrict__ sv_p, const float* __restrict__ rate_p,
              const float* __restrict__ ndt_p, const float* __restrict__ thr_p,
              const float* __restrict__ noise_p, const float* __restrict__ dt_p,
              const int* __restrict__ nw_p, float* __restrict__ out,
              int round, int t0) {
  int nw = *nw_p;
  float rate = *rate_p, ndt = *ndt_p, thr = *thr_p,
        noise = *noise_p, dt = *dt_p;
  float rate_dt = __fmul_rn(rate, dt);
  float sqrt_dt = __fsqrt_rn(dt);

  int lane = threadIdx.x & 63;
  uint32_t wave = blockIdx.x * (BLOCK / 64) + (threadIdx.x >> 6);
  uint32_t nwaves = gridDim.x * (BLOCK / 64);
  uint32_t count = g_cnt[round];

  for (uint32_t k = wave; k < count; k += nwaves) {
    uint2 e = g_list[round & 1][k];
    int i = (int)e.x;
    float p = __uint_as_float(e.y);       // wave-uniform from here on
    int t = t0;
    int rts_i = NSTEPS;
    bool done = false;
    while (!done) {
      int valid = NSTEPS - t; if (valid > 64) valid = 64;
      int tl = t + (lane < valid ? lane : valid - 1);
      uint2 kk = g_keys[tl];
      uint32_t b1, b2;
      tf2x32(kk.x, kk.y, 0u, (uint32_t)i, b1, b2);
      float z = normal_from_bits(b1 ^ b2);
      float q = __fmul_rn(__fadd_rn(rate_dt, __fmul_rn(noise, z)), sqrt_dt);
      int cross = -1;
      for (int j = 0; j < valid; ++j) {   // branchless exact sequential scan
        float qj = __shfl(q, j);
        float pn = __fadd_rn(p, qj);
        bool still = (cross < 0);
        p = still ? pn : p;
        bool c = still & !(fabsf(p) < thr);
        cross = c ? j : cross;
      }
      if (cross >= 0) { rts_i = t + cross + 1; done = true; }
      else { t += valid; if (t >= NSTEPS) done = true; }
    }
    if (lane == 0) {
      out[i] = __fadd_rn(ndt, __fmul_rn((float)rts_i, dt));
      out[nw + i] = (p <= -thr) ? 0.0f : 1.0f;
    }
  }
}

extern "C" void kernel_launch(void* const* d_in, const int* in_sizes, int n_in,
                              void* d_out, int out_size, void* d_ws, size_t ws_size,
                              hipStream_t stream) {
  const float* sv    = (const float*)d_in[0];
  const float* rate  = (const float*)d_in[1];
  const float* ndt   = (const float*)d_in[2];
  const float* thr   = (const float*)d_in[3];
  const float* noise = (const float*)d_in[4];
  const float* dt    = (const float*)d_in[5];
  const int*   nw    = (const int*)d_in[6];
  float* out = (float*)d_out;

  init_kernel<<<NKEYS / 256, 256, 0, stream>>>();
  for (int r = 0; r < NDENSE; ++r) {
    ddm_round<<<NBD, BLOCK, 0, stream>>>(sv, rate, ndt, thr, noise, dt, nw, out,
                                         r, r * CHUNK);
  }
  ddm_tail<<<NBT, BLOCK, 0, stream>>>(sv, rate, ndt, thr, noise, dt, nw, out,
                                      NDENSE, NDENSE * CHUNK);
}